// Round 6
// baseline (306.631 us; speedup 1.0000x reference)
//
#include <hip/hip_runtime.h>
#include <hip/hip_bf16.h>

typedef __bf16 bf16x8 __attribute__((ext_vector_type(8)));
typedef float  f32x4  __attribute__((ext_vector_type(4)));

#define HH    8
#define NN    4096
#define FIN   512
#define FOUT  64
#define ALPHA 0.2f

// ---------------------------------------------------------------------------
// k0: W[h][f][o] (fp32, 1 MB) -> WT[h][o][f] (bf16)
// ---------------------------------------------------------------------------
__global__ void k_transpose_w(const float* __restrict__ Wsrc,
                              __hip_bfloat16* __restrict__ WT) {
    int idx = blockIdx.x * blockDim.x + threadIdx.x;  // H*FIN*FOUT = 262144
    int h   = idx / (FIN * FOUT);
    int rem = idx % (FIN * FOUT);
    int f   = rem / FOUT;
    int o   = rem % FOUT;
    WT[((size_t)h * FOUT + o) * FIN + f] = __float2bfloat16(Wsrc[idx]);
}

// ---------------------------------------------------------------------------
// k_proj: block = 256 thr = 4 waves = 4 heads; grid = (256 tiles, 2 hgroups).
// One 16-row feature tile staged in LDS (bf16) shared by the 4 head-waves.
// WT (512 KB bf16 total) is L2-resident across all blocks.
// A-frag: lane holds A[m=lane&15][k=quad*8+j]; B-frag: B[k=quad*8+j][n=lane&15]
// C/D   : lane holds C[row=quad*4+r][col=lane&15]   (HW-verified layouts)
// ---------------------------------------------------------------------------
__global__ __launch_bounds__(256) void k_proj(
    const float* __restrict__ feat,
    const __hip_bfloat16* __restrict__ WT,
    const float* __restrict__ a_src,
    const float* __restrict__ a_dst,
    __hip_bfloat16* __restrict__ WhT,
    float* __restrict__ srcv, float* __restrict__ dstv) {
    // +8 bf16 pad -> row stride 1040 B: 2-way bank aliasing only (free)
    __shared__ alignas(16) __hip_bfloat16 lfeat[16][520];

    const int tid  = threadIdx.x;
    const int tile = blockIdx.x;          // 16 rows per block

    // Stage feat tile: 256 threads x 8 passes x float4, fp32 -> bf16
#pragma unroll
    for (int p = 0; p < 8; ++p) {
        int row = p * 2 + (tid >> 7);
        int col = (tid & 127) * 4;
        float4 f = *(const float4*)(feat + (size_t)(tile * 16 + row) * FIN + col);
        __hip_bfloat16* dst = &lfeat[row][col];
        dst[0] = __float2bfloat16(f.x); dst[1] = __float2bfloat16(f.y);
        dst[2] = __float2bfloat16(f.z); dst[3] = __float2bfloat16(f.w);
    }
    __syncthreads();

    const int h     = blockIdx.y * 4 + (tid >> 6);   // head = hgroup*4 + wave
    const int lane  = tid & 63;
    const int row16 = lane & 15;
    const int quad  = lane >> 4;
    const int nbase = tile * 16;

    const unsigned short* WTu = (const unsigned short*)WT + (size_t)h * FOUT * FIN;

    f32x4 acc[4] = {};
    for (int k0 = 0; k0 < FIN; k0 += 32) {
        bf16x8 a = *(const bf16x8*)&lfeat[row16][k0 + quad * 8];
#pragma unroll
        for (int ot = 0; ot < 4; ++ot) {
            bf16x8 b = *(const bf16x8*)(WTu + (size_t)(ot * 16 + row16) * FIN + k0 + quad * 8);
            acc[ot] = __builtin_amdgcn_mfma_f32_16x16x32_bf16(a, b, acc[ot], 0, 0, 0);
        }
    }

    // WhT[h][o][n] bf16 (B operand of the attention GEMM)
#pragma unroll
    for (int ot = 0; ot < 4; ++ot) {
        int o = ot * 16 + row16;
#pragma unroll
        for (int r = 0; r < 4; ++r) {
            int n = nbase + quad * 4 + r;
            WhT[((size_t)h * FOUT + o) * NN + n] = __float2bfloat16(acc[ot][r]);
        }
    }

    // src/dst logits from fp32 accumulators
    float asv[4], adv[4];
#pragma unroll
    for (int ot = 0; ot < 4; ++ot) {
        asv[ot] = a_src[h * FOUT + ot * 16 + row16];
        adv[ot] = a_dst[h * FOUT + ot * 16 + row16];
    }
#pragma unroll
    for (int r = 0; r < 4; ++r) {
        float ss = 0.f, dd = 0.f;
#pragma unroll
        for (int ot = 0; ot < 4; ++ot) {
            ss += acc[ot][r] * asv[ot];
            dd += acc[ot][r] * adv[ot];
        }
        ss += __shfl_xor(ss, 1); ss += __shfl_xor(ss, 2);
        ss += __shfl_xor(ss, 4); ss += __shfl_xor(ss, 8);
        dd += __shfl_xor(dd, 1); dd += __shfl_xor(dd, 2);
        dd += __shfl_xor(dd, 4); dd += __shfl_xor(dd, 8);
        if (row16 == 0) {
            int n = nbase + quad * 4 + r;
            srcv[h * NN + n] = ss;
            dstv[h * NN + n] = dd;
        }
    }
}

// ---------------------------------------------------------------------------
// k_flash: masked softmax attention + ELU.
// Block = 512 thr = 8 waves = 4 local heads x 2 j-segments (2048 cols each).
// Grid = 512 blocks, bx-swizzled so the two head-group blocks of the same
// tile land on the same XCD (round-robin stride 8) ~simultaneously -> the
// twin's adjacency reads hit L2 instead of L3/HBM.
// Depth-2 register prefetch of adj/dst/B: R5 counters showed ~5-7k cycles
// latency per iteration (memory-level-parallelism bound, VGPR=36 -> compiler
// did not pipeline). launch_bounds(512,4): <=128 VGPR, 16 waves/CU floor.
// Row-sum l via a 5th MFMA vs all-ones B-frag. Segs combine in-block via LDS.
// ---------------------------------------------------------------------------
__global__ __launch_bounds__(512, 4) void k_flash(
    const int* __restrict__ adj,
    const float* __restrict__ srcv, const float* __restrict__ dstv,
    const unsigned short* __restrict__ WhT,  // [H][FOUT][NN] bf16 bits
    float* __restrict__ out) {
    __shared__ float lds_acc[4][1024];
    __shared__ float lds_l[4][16];

    const int tid   = threadIdx.x;
    const int wv    = tid >> 6;              // 0..7
    const int lane  = tid & 63;
    const int row16 = lane & 15;
    const int quad  = lane >> 4;
    const int h4    = wv & 3;                // local head
    const int seg   = wv >> 2;               // j-segment 0..1 (2048 cols each)

    // XCD-pair swizzle: (tile, hg=0) at bx and (tile, hg=1) at bx+8 -> same XCD
    const int bx   = blockIdx.x;
    const int hg   = (bx >> 3) & 1;
    const int tile = ((bx >> 4) << 3) | (bx & 7);

    const int h   = hg * 4 + h4;
    const int i   = tile * 16 + row16;
    const int shl = quad * 8;

    const float           si     = srcv[h * NN + i];
    const int*            adjrow = adj + (size_t)i * NN + seg * 2048;
    const float*          dsth   = dstv + h * NN + seg * 2048;
    const unsigned short* wh     = WhT + (size_t)h * FOUT * NN + seg * 2048;

    bf16x8 ones;
#pragma unroll
    for (int k = 0; k < 8; ++k) ones[k] = (__bf16)1.0f;

    f32x4 acc[4] = {};
    f32x4 accl   = {};

    // depth-2 prefetch buffers
    int4   pa0[2], pa1[2];
    float4 pd0[2], pd1[2];
    bf16x8 pb[2][4];

    auto issue = [&](int t, int s) {
        int tc = t < 64 ? t : 63;            // clamp: tail prefetch stays in-bounds
        int jj = tc * 32 + shl;
        pa0[s] = *(const int4*)(adjrow + jj);
        pa1[s] = *(const int4*)(adjrow + jj + 4);
        pd0[s] = *(const float4*)(dsth + jj);
        pd1[s] = *(const float4*)(dsth + jj + 4);
#pragma unroll
        for (int ot = 0; ot < 4; ++ot)
            pb[s][ot] = *(const bf16x8*)(wh + (size_t)(ot * 16 + row16) * NN + jj);
    };

    auto consume = [&](int s) {
        const float dv[8] = {pd0[s].x, pd0[s].y, pd0[s].z, pd0[s].w,
                             pd1[s].x, pd1[s].y, pd1[s].z, pd1[s].w};
        const int   av[8] = {pa0[s].x, pa0[s].y, pa0[s].z, pa0[s].w,
                             pa1[s].x, pa1[s].y, pa1[s].z, pa1[s].w};
        bf16x8 af;
#pragma unroll
        for (int k = 0; k < 8; ++k) {
            float tt = si + dv[k];
            float e  = fmaxf(tt, tt * ALPHA);          // LeakyReLU (alpha<1)
            float p  = av[k] > 0 ? __expf(e) : 0.f;
            af[k] = (__bf16)p;
        }
#pragma unroll
        for (int ot = 0; ot < 4; ++ot)
            acc[ot] = __builtin_amdgcn_mfma_f32_16x16x32_bf16(af, pb[s][ot], acc[ot], 0, 0, 0);
        accl = __builtin_amdgcn_mfma_f32_16x16x32_bf16(af, ones, accl, 0, 0, 0);
    };

    issue(0, 0);
    issue(1, 1);
#pragma unroll 1
    for (int t = 0; t < 64; t += 2) {
        consume(0); issue(t + 2, 0);
        consume(1); issue(t + 3, 1);
    }

    // combine the two j-segments in LDS; seg-0 waves write output
    if (seg == 1) {
        float* la = &lds_acc[h4][0];
#pragma unroll
        for (int ot = 0; ot < 4; ++ot)
#pragma unroll
            for (int r = 0; r < 4; ++r)
                la[(quad * 4 + r) * 64 + ot * 16 + row16] = acc[ot][r];
        if (row16 == 0) {
#pragma unroll
            for (int r = 0; r < 4; ++r)
                lds_l[h4][quad * 4 + r] = accl[r];
        }
    }
    __syncthreads();

    if (seg == 0) {
        const float* la = &lds_acc[h4][0];
#pragma unroll
        for (int r = 0; r < 4; ++r) {
            int   qr = quad * 4 + r;
            float l  = accl[r] + lds_l[h4][qr];
            float rl = 1.0f / l;
#pragma unroll
            for (int ot = 0; ot < 4; ++ot) {
                float v = (acc[ot][r] + la[qr * 64 + ot * 16 + row16]) * rl;
                float y = v > 0.f ? v : __expf(v) - 1.f;  // ELU
                out[(size_t)(tile * 16 + qr) * (HH * FOUT) + h * FOUT + ot * 16 + row16] = y;
            }
        }
    }
}

// ---------------------------------------------------------------------------
extern "C" void kernel_launch(void* const* d_in, const int* in_sizes, int n_in,
                              void* d_out, int out_size, void* d_ws, size_t ws_size,
                              hipStream_t stream) {
    const float* features = (const float*)d_in[0];
    const int*   adj      = (const int*)d_in[1];
    const float* W        = (const float*)d_in[2];
    const float* a_src    = (const float*)d_in[3];
    const float* a_dst    = (const float*)d_in[4];
    float*       out      = (float*)d_out;   // reference output dtype = fp32

    // Workspace: 4.75 MB total (proven within ws_size; 6.75 MB was not)
    char* ws = (char*)d_ws;
    __hip_bfloat16* WT   = (__hip_bfloat16*)(ws);                      // 512 KB
    __hip_bfloat16* WhT  = (__hip_bfloat16*)(ws + (512 << 10));        // 4 MB
    float*          srcv = (float*)(ws + (512 << 10) + (4 << 20));     // 128 KB
    float*          dstv = (float*)(ws + (512 << 10) + (4 << 20) + (128 << 10));  // 128 KB

    k_transpose_w<<<dim3((HH * FIN * FOUT) / 256), 256, 0, stream>>>(W, WT);
    k_proj<<<dim3(NN / 16, 2), 256, 0, stream>>>(features, WT, a_src, a_dst,
                                                 WhT, srcv, dstv);
    k_flash<<<dim3(512), 512, 0, stream>>>(adj, srcv, dstv,
                                           (const unsigned short*)WhT, out);
}

// Round 7
// 239.764 us; speedup vs baseline: 1.2789x; 1.2789x over previous
//
#include <hip/hip_runtime.h>
#include <hip/hip_bf16.h>

typedef __bf16 bf16x8 __attribute__((ext_vector_type(8)));
typedef float  f32x4  __attribute__((ext_vector_type(4)));

#define HH    8
#define NN    4096
#define FIN   512
#define FOUT  64
#define ALPHA 0.2f

// ---------------------------------------------------------------------------
// k0: W[h][f][o] (fp32) -> WT[h][o][f] (bf16), coalesced via LDS 64x64 tile.
// (Previous version wrote WT at 1KB stride: one cache line per lane. This one
// reads o-contiguous and writes f-contiguous.)
// Grid = 8 heads x 8 f-tiles = 64 blocks x 256 thr.
// ---------------------------------------------------------------------------
__global__ __launch_bounds__(256) void k_transpose_w(
    const float* __restrict__ Wsrc, __hip_bfloat16* __restrict__ WT) {
    __shared__ __hip_bfloat16 lt[64][65];
    const int h  = blockIdx.x >> 3;
    const int f0 = (blockIdx.x & 7) * 64;
    const int tid = threadIdx.x;
#pragma unroll
    for (int p = 0; p < 16; ++p) {
        int f = p * 4 + (tid >> 6);          // 0..63
        int o = tid & 63;
        lt[f][o] = __float2bfloat16(Wsrc[((size_t)h * FIN + f0 + f) * FOUT + o]);
    }
    __syncthreads();
#pragma unroll
    for (int p = 0; p < 16; ++p) {
        int o = p * 4 + (tid >> 6);
        int f = tid & 63;
        WT[((size_t)h * FOUT + o) * FIN + f0 + f] = lt[f][o];
    }
}

// ---------------------------------------------------------------------------
// k_proj: block = 256 thr = 4 waves = 4 heads; grid = (256 tiles, 2 hgroups).
// One 16-row feature tile staged in LDS (bf16) shared by the 4 head-waves.
// A-frag: lane holds A[m=lane&15][k=quad*8+j]; B-frag: B[k=quad*8+j][n=lane&15]
// C/D   : lane holds C[row=quad*4+r][col=lane&15]   (HW-verified layouts)
// ---------------------------------------------------------------------------
__global__ __launch_bounds__(256) void k_proj(
    const float* __restrict__ feat,
    const __hip_bfloat16* __restrict__ WT,
    const float* __restrict__ a_src,
    const float* __restrict__ a_dst,
    __hip_bfloat16* __restrict__ WhT,
    float* __restrict__ srcv, float* __restrict__ dstv) {
    __shared__ alignas(16) __hip_bfloat16 lfeat[16][520];

    const int tid  = threadIdx.x;
    const int tile = blockIdx.x;          // 16 rows per block

#pragma unroll
    for (int p = 0; p < 8; ++p) {
        int row = p * 2 + (tid >> 7);
        int col = (tid & 127) * 4;
        float4 f = *(const float4*)(feat + (size_t)(tile * 16 + row) * FIN + col);
        __hip_bfloat16* dst = &lfeat[row][col];
        dst[0] = __float2bfloat16(f.x); dst[1] = __float2bfloat16(f.y);
        dst[2] = __float2bfloat16(f.z); dst[3] = __float2bfloat16(f.w);
    }
    __syncthreads();

    const int h     = blockIdx.y * 4 + (tid >> 6);
    const int lane  = tid & 63;
    const int row16 = lane & 15;
    const int quad  = lane >> 4;
    const int nbase = tile * 16;

    const unsigned short* WTu = (const unsigned short*)WT + (size_t)h * FOUT * FIN;

    f32x4 acc[4] = {};
    for (int k0 = 0; k0 < FIN; k0 += 32) {
        bf16x8 a = *(const bf16x8*)&lfeat[row16][k0 + quad * 8];
#pragma unroll
        for (int ot = 0; ot < 4; ++ot) {
            bf16x8 b = *(const bf16x8*)(WTu + (size_t)(ot * 16 + row16) * FIN + k0 + quad * 8);
            acc[ot] = __builtin_amdgcn_mfma_f32_16x16x32_bf16(a, b, acc[ot], 0, 0, 0);
        }
    }

#pragma unroll
    for (int ot = 0; ot < 4; ++ot) {
        int o = ot * 16 + row16;
#pragma unroll
        for (int r = 0; r < 4; ++r) {
            int n = nbase + quad * 4 + r;
            WhT[((size_t)h * FOUT + o) * NN + n] = __float2bfloat16(acc[ot][r]);
        }
    }

    float asv[4], adv[4];
#pragma unroll
    for (int ot = 0; ot < 4; ++ot) {
        asv[ot] = a_src[h * FOUT + ot * 16 + row16];
        adv[ot] = a_dst[h * FOUT + ot * 16 + row16];
    }
#pragma unroll
    for (int r = 0; r < 4; ++r) {
        float ss = 0.f, dd = 0.f;
#pragma unroll
        for (int ot = 0; ot < 4; ++ot) {
            ss += acc[ot][r] * asv[ot];
            dd += acc[ot][r] * adv[ot];
        }
        ss += __shfl_xor(ss, 1); ss += __shfl_xor(ss, 2);
        ss += __shfl_xor(ss, 4); ss += __shfl_xor(ss, 8);
        dd += __shfl_xor(dd, 1); dd += __shfl_xor(dd, 2);
        dd += __shfl_xor(dd, 4); dd += __shfl_xor(dd, 8);
        if (row16 == 0) {
            int n = nbase + quad * 4 + r;
            srcv[h * NN + n] = ss;
            dstv[h * NN + n] = dd;
        }
    }
}

// ---------------------------------------------------------------------------
// k_flash: masked softmax attention + ELU.  M=32 B-reuse version.
// R3/R5/R6 invariant: ~60 cyc per vmem instruction per CU (memory-pipeline
// bound; not HBM BW, not VALU, not wave count). B-fragment lines (64/iter)
// dominate and are independent of M -> double M to 32 rows/wave, halving
// wave-iters and total line traffic for the same output.
// Block = 1024 thr = 16 waves = 4 local heads x 4 j-segments (1024 j, 32 it).
// Grid = 128 tiles x 2 head-groups = 256 blocks, XCD-pair swizzled (R6:
// FETCH 84->50 MB proven). Row-sums via MFMA vs all-ones B. Segments combine
// through a 64KB LDS tree (1,3 stash; 0,2 add; 2 stash; 0 add+write).
// ---------------------------------------------------------------------------
__global__ __launch_bounds__(1024, 4) void k_flash(
    const int* __restrict__ adj,
    const float* __restrict__ srcv, const float* __restrict__ dstv,
    const unsigned short* __restrict__ WhT,  // [H][FOUT][NN] bf16 bits
    float* __restrict__ out) {
    __shared__ float lds_stash[2][4][2048];  // [buf][h4][(f*16+qr)*64 + c]
    __shared__ float lds_l[2][4][32];        // [buf][h4][f*16+qr]

    const int tid   = threadIdx.x;
    const int wv    = tid >> 6;              // 0..15
    const int lane  = tid & 63;
    const int row16 = lane & 15;
    const int quad  = lane >> 4;
    const int h4    = wv & 3;
    const int seg   = wv >> 2;               // 0..3, 1024 j each

    // XCD-pair swizzle: (tile, hg=0) at bx, (tile, hg=1) at bx+8 -> same XCD
    const int bx   = blockIdx.x;             // 0..255
    const int hg   = (bx >> 3) & 1;
    const int tile = ((bx >> 4) << 3) | (bx & 7);   // 0..127, 32 rows each

    const int h   = hg * 4 + h4;
    const int i0  = tile * 32 + row16;
    const int i1  = i0 + 16;
    const int shl = quad * 8;

    const float           si0  = srcv[h * NN + i0];
    const float           si1  = srcv[h * NN + i1];
    const int*            ar0  = adj + (size_t)i0 * NN + seg * 1024;
    const int*            ar1  = adj + (size_t)i1 * NN + seg * 1024;
    const float*          dsth = dstv + h * NN + seg * 1024;
    const unsigned short* wh   = WhT + (size_t)h * FOUT * NN + seg * 1024;

    bf16x8 ones;
#pragma unroll
    for (int k = 0; k < 8; ++k) ones[k] = (__bf16)1.0f;

    f32x4 acc0[4] = {}, acc1[4] = {};
    f32x4 accl0 = {}, accl1 = {};

#pragma unroll 1
    for (int t = 0; t < 32; ++t) {
        int jj = t * 32 + shl;
        int4   a00 = *(const int4*)(ar0 + jj);
        int4   a01 = *(const int4*)(ar0 + jj + 4);
        int4   a10 = *(const int4*)(ar1 + jj);
        int4   a11 = *(const int4*)(ar1 + jj + 4);
        float4 d0  = *(const float4*)(dsth + jj);
        float4 d1  = *(const float4*)(dsth + jj + 4);
        const float dv[8] = {d0.x, d0.y, d0.z, d0.w, d1.x, d1.y, d1.z, d1.w};
        const int   av0[8] = {a00.x, a00.y, a00.z, a00.w, a01.x, a01.y, a01.z, a01.w};
        const int   av1[8] = {a10.x, a10.y, a10.z, a10.w, a11.x, a11.y, a11.z, a11.w};
        bf16x8 af0, af1;
#pragma unroll
        for (int k = 0; k < 8; ++k) {
            float t0 = si0 + dv[k];
            float e0 = fmaxf(t0, t0 * ALPHA);
            af0[k] = (__bf16)(av0[k] > 0 ? __expf(e0) : 0.f);
            float t1 = si1 + dv[k];
            float e1 = fmaxf(t1, t1 * ALPHA);
            af1[k] = (__bf16)(av1[k] > 0 ? __expf(e1) : 0.f);
        }
        bf16x8 b[4];
#pragma unroll
        for (int ot = 0; ot < 4; ++ot)
            b[ot] = *(const bf16x8*)(wh + (size_t)(ot * 16 + row16) * NN + jj);
#pragma unroll
        for (int ot = 0; ot < 4; ++ot) {
            acc0[ot] = __builtin_amdgcn_mfma_f32_16x16x32_bf16(af0, b[ot], acc0[ot], 0, 0, 0);
            acc1[ot] = __builtin_amdgcn_mfma_f32_16x16x32_bf16(af1, b[ot], acc1[ot], 0, 0, 0);
        }
        accl0 = __builtin_amdgcn_mfma_f32_16x16x32_bf16(af0, ones, accl0, 0, 0, 0);
        accl1 = __builtin_amdgcn_mfma_f32_16x16x32_bf16(af1, ones, accl1, 0, 0, 0);
    }

    // ---- segment-combine tree in LDS ----
    // P1: seg1 -> buf0, seg3 -> buf1
    if (seg == 1 || seg == 3) {
        int buf = (seg - 1) >> 1;
        float* st = &lds_stash[buf][h4][0];
#pragma unroll
        for (int ot = 0; ot < 4; ++ot)
#pragma unroll
            for (int r = 0; r < 4; ++r) {
                st[(quad * 4 + r) * 64 + ot * 16 + row16]        = acc0[ot][r];
                st[(16 + quad * 4 + r) * 64 + ot * 16 + row16]   = acc1[ot][r];
            }
        if (row16 == 0) {
#pragma unroll
            for (int r = 0; r < 4; ++r) {
                lds_l[buf][h4][quad * 4 + r]      = accl0[r];
                lds_l[buf][h4][16 + quad * 4 + r] = accl1[r];
            }
        }
    }
    __syncthreads();
    // P2: seg0 += buf0, seg2 += buf1
    if (seg == 0 || seg == 2) {
        int buf = seg >> 1;
        const float* st = &lds_stash[buf][h4][0];
#pragma unroll
        for (int ot = 0; ot < 4; ++ot)
#pragma unroll
            for (int r = 0; r < 4; ++r) {
                acc0[ot][r] += st[(quad * 4 + r) * 64 + ot * 16 + row16];
                acc1[ot][r] += st[(16 + quad * 4 + r) * 64 + ot * 16 + row16];
            }
#pragma unroll
        for (int r = 0; r < 4; ++r) {
            accl0[r] += lds_l[buf][h4][quad * 4 + r];
            accl1[r] += lds_l[buf][h4][16 + quad * 4 + r];
        }
    }
    __syncthreads();
    // P3: seg2 -> buf0
    if (seg == 2) {
        float* st = &lds_stash[0][h4][0];
#pragma unroll
        for (int ot = 0; ot < 4; ++ot)
#pragma unroll
            for (int r = 0; r < 4; ++r) {
                st[(quad * 4 + r) * 64 + ot * 16 + row16]      = acc0[ot][r];
                st[(16 + quad * 4 + r) * 64 + ot * 16 + row16] = acc1[ot][r];
            }
        if (row16 == 0) {
#pragma unroll
            for (int r = 0; r < 4; ++r) {
                lds_l[0][h4][quad * 4 + r]      = accl0[r];
                lds_l[0][h4][16 + quad * 4 + r] = accl1[r];
            }
        }
    }
    __syncthreads();
    // P4: seg0 final add + epilogue
    if (seg == 0) {
        const float* st = &lds_stash[0][h4][0];
#pragma unroll
        for (int r = 0; r < 4; ++r) {
            int qr = quad * 4 + r;
            float l0 = accl0[r] + lds_l[0][h4][qr];
            float l1 = accl1[r] + lds_l[0][h4][16 + qr];
            float rl0 = 1.0f / l0, rl1 = 1.0f / l1;
#pragma unroll
            for (int ot = 0; ot < 4; ++ot) {
                int c = ot * 16 + row16;
                float v0 = (acc0[ot][r] + st[qr * 64 + c]) * rl0;
                float v1 = (acc1[ot][r] + st[(16 + qr) * 64 + c]) * rl1;
                float y0 = v0 > 0.f ? v0 : __expf(v0) - 1.f;
                float y1 = v1 > 0.f ? v1 : __expf(v1) - 1.f;
                out[(size_t)(tile * 32 + qr) * (HH * FOUT) + h * FOUT + c]      = y0;
                out[(size_t)(tile * 32 + 16 + qr) * (HH * FOUT) + h * FOUT + c] = y1;
            }
        }
    }
}

// ---------------------------------------------------------------------------
extern "C" void kernel_launch(void* const* d_in, const int* in_sizes, int n_in,
                              void* d_out, int out_size, void* d_ws, size_t ws_size,
                              hipStream_t stream) {
    const float* features = (const float*)d_in[0];
    const int*   adj      = (const int*)d_in[1];
    const float* W        = (const float*)d_in[2];
    const float* a_src    = (const float*)d_in[3];
    const float* a_dst    = (const float*)d_in[4];
    float*       out      = (float*)d_out;

    // Workspace: 4.75 MB total (proven within ws_size; 6.75 MB was not)
    char* ws = (char*)d_ws;
    __hip_bfloat16* WT   = (__hip_bfloat16*)(ws);                      // 512 KB
    __hip_bfloat16* WhT  = (__hip_bfloat16*)(ws + (512 << 10));        // 4 MB
    float*          srcv = (float*)(ws + (512 << 10) + (4 << 20));     // 128 KB
    float*          dstv = (float*)(ws + (512 << 10) + (4 << 20) + (128 << 10));  // 128 KB

    k_transpose_w<<<dim3(64), 256, 0, stream>>>(W, WT);
    k_proj<<<dim3(NN / 16, 2), 256, 0, stream>>>(features, WT, a_src, a_dst,
                                                 WhT, srcv, dstv);
    k_flash<<<dim3(256), 1024, 0, stream>>>(adj, srcv, dstv,
                                            (const unsigned short*)WhT, out);
}

// Round 8
// 196.353 us; speedup vs baseline: 1.5616x; 1.2211x over previous
//
#include <hip/hip_runtime.h>
#include <hip/hip_bf16.h>

typedef __bf16 bf16x8 __attribute__((ext_vector_type(8)));
typedef float  f32x4  __attribute__((ext_vector_type(4)));
typedef unsigned short u16x8 __attribute__((ext_vector_type(8)));

#define HH    8
#define NN    4096
#define FIN   512
#define FOUT  64
#define ALPHA 0.2f

// ---------------------------------------------------------------------------
// k_pack: in-place adjacency bit-pack. Block b owns elements [b*8192,+8192)
// (= rows 2b, 2b+1) and packs them into 1 KB of bits written at the START of
// its own region (byte b*32768). Write-after-read is within-block only
// (guarded by __syncthreads); no cross-block hazard. Bit j%8 of byte
// (i>>1)*32768 + (i&1)*512 + j/8  ==  adj[i][j] > 0.
// ---------------------------------------------------------------------------
__global__ __launch_bounds__(256) void k_pack(int* __restrict__ adj) {
    const size_t base = (size_t)blockIdx.x * 8192;
    const int    tid  = threadIdx.x;
    unsigned m = 0;
#pragma unroll
    for (int p = 0; p < 8; ++p) {
        int4 v = *(const int4*)(adj + base + tid * 32 + p * 4);
        m |= (unsigned)(v.x > 0) << (p * 4);
        m |= (unsigned)(v.y > 0) << (p * 4 + 1);
        m |= (unsigned)(v.z > 0) << (p * 4 + 2);
        m |= (unsigned)(v.w > 0) << (p * 4 + 3);
    }
    __syncthreads();
    ((unsigned*)adj)[base + tid] = m;   // dword tid of the block's 1-KB mask
}

// ---------------------------------------------------------------------------
// k0: W[h][f][o] (fp32) -> WT[h][o][f] (bf16), coalesced via LDS 64x64 tile.
// ---------------------------------------------------------------------------
__global__ __launch_bounds__(256) void k_transpose_w(
    const float* __restrict__ Wsrc, __hip_bfloat16* __restrict__ WT) {
    __shared__ __hip_bfloat16 lt[64][65];
    const int h  = blockIdx.x >> 3;
    const int f0 = (blockIdx.x & 7) * 64;
    const int tid = threadIdx.x;
#pragma unroll
    for (int p = 0; p < 16; ++p) {
        int f = p * 4 + (tid >> 6);
        int o = tid & 63;
        lt[f][o] = __float2bfloat16(Wsrc[((size_t)h * FIN + f0 + f) * FOUT + o]);
    }
    __syncthreads();
#pragma unroll
    for (int p = 0; p < 16; ++p) {
        int o = p * 4 + (tid >> 6);
        int f = tid & 63;
        WT[((size_t)h * FOUT + o) * FIN + f0 + f] = lt[f][o];
    }
}

// ---------------------------------------------------------------------------
// k_proj: per head h: Wh = feat @ W[h], fp32 acc via bf16 MFMA.
// Writes WhT[h][o][n] (bf16), srcv[h][n] (fp32), and the attention-logit
// exp-factor tables Ebf[h][n]=bf16(exp(dst)), Fbf[h][n]=bf16(exp(0.2*dst)).
// Block = 256 thr = 4 waves = 4 heads; grid = (256 tiles, 2 hgroups).
// ---------------------------------------------------------------------------
__global__ __launch_bounds__(256) void k_proj(
    const float* __restrict__ feat,
    const __hip_bfloat16* __restrict__ WT,
    const float* __restrict__ a_src,
    const float* __restrict__ a_dst,
    __hip_bfloat16* __restrict__ WhT,
    float* __restrict__ srcv,
    unsigned short* __restrict__ Ebf, unsigned short* __restrict__ Fbf) {
    __shared__ alignas(16) __hip_bfloat16 lfeat[16][520];

    const int tid  = threadIdx.x;
    const int tile = blockIdx.x;

#pragma unroll
    for (int p = 0; p < 8; ++p) {
        int row = p * 2 + (tid >> 7);
        int col = (tid & 127) * 4;
        float4 f = *(const float4*)(feat + (size_t)(tile * 16 + row) * FIN + col);
        __hip_bfloat16* dst = &lfeat[row][col];
        dst[0] = __float2bfloat16(f.x); dst[1] = __float2bfloat16(f.y);
        dst[2] = __float2bfloat16(f.z); dst[3] = __float2bfloat16(f.w);
    }
    __syncthreads();

    const int h     = blockIdx.y * 4 + (tid >> 6);
    const int lane  = tid & 63;
    const int row16 = lane & 15;
    const int quad  = lane >> 4;
    const int nbase = tile * 16;

    const unsigned short* WTu = (const unsigned short*)WT + (size_t)h * FOUT * FIN;

    f32x4 acc[4] = {};
    for (int k0 = 0; k0 < FIN; k0 += 32) {
        bf16x8 a = *(const bf16x8*)&lfeat[row16][k0 + quad * 8];
#pragma unroll
        for (int ot = 0; ot < 4; ++ot) {
            bf16x8 b = *(const bf16x8*)(WTu + (size_t)(ot * 16 + row16) * FIN + k0 + quad * 8);
            acc[ot] = __builtin_amdgcn_mfma_f32_16x16x32_bf16(a, b, acc[ot], 0, 0, 0);
        }
    }

#pragma unroll
    for (int ot = 0; ot < 4; ++ot) {
        int o = ot * 16 + row16;
#pragma unroll
        for (int r = 0; r < 4; ++r) {
            int n = nbase + quad * 4 + r;
            WhT[((size_t)h * FOUT + o) * NN + n] = __float2bfloat16(acc[ot][r]);
        }
    }

    float asv[4], adv[4];
#pragma unroll
    for (int ot = 0; ot < 4; ++ot) {
        asv[ot] = a_src[h * FOUT + ot * 16 + row16];
        adv[ot] = a_dst[h * FOUT + ot * 16 + row16];
    }
#pragma unroll
    for (int r = 0; r < 4; ++r) {
        float ss = 0.f, dd = 0.f;
#pragma unroll
        for (int ot = 0; ot < 4; ++ot) {
            ss += acc[ot][r] * asv[ot];
            dd += acc[ot][r] * adv[ot];
        }
        ss += __shfl_xor(ss, 1); ss += __shfl_xor(ss, 2);
        ss += __shfl_xor(ss, 4); ss += __shfl_xor(ss, 8);
        dd += __shfl_xor(dd, 1); dd += __shfl_xor(dd, 2);
        dd += __shfl_xor(dd, 4); dd += __shfl_xor(dd, 8);
        if (row16 == 0) {
            int n = nbase + quad * 4 + r;
            srcv[h * NN + n] = ss;
            __bf16 e = (__bf16)__expf(dd);
            __bf16 f = (__bf16)__expf(ALPHA * dd);
            Ebf[h * NN + n] = __builtin_bit_cast(unsigned short, e);
            Fbf[h * NN + n] = __builtin_bit_cast(unsigned short, f);
        }
    }
}

// ---------------------------------------------------------------------------
// k_flash: masked softmax attention + ELU. M=32, bit-mask, exp-free hot loop.
// p_ij = (si+dj>=0) ? exp(si)exp(dj) : exp(.2si)exp(.2dj); branch decided by
// integer compare of bf16 bits (monotone for positive floats): Ed >= exp(-si).
// Per-row factors cancel in softmax ratio, so only Ed/Fd bf16 error remains.
// Block = 1024 thr = 16 waves = 4 heads x 4 j-segments; grid 256 (XCD-pair
// swizzle). Mask bits staged once into LDS (16.9 KB, unioned with the 64-KB
// stash; bank-padded [4][32][33]). Lines/iter: B 64 + E/F 2 (was 196).
// ---------------------------------------------------------------------------
__global__ __launch_bounds__(1024, 4) void k_flash(
    const unsigned* __restrict__ maskp,      // packed bits, lives in adj buffer
    const float* __restrict__ srcv,
    const unsigned short* __restrict__ Ebf,
    const unsigned short* __restrict__ Fbf,
    const unsigned short* __restrict__ WhT,  // [H][FOUT][NN] bf16 bits
    float* __restrict__ out) {
    __shared__ float lds_stash[2][4][2048];  // 64 KB; first 16.9 KB = mask during loop
    __shared__ float lds_l[2][4][32];

    unsigned* lmask = (unsigned*)&lds_stash[0][0][0];   // [4][32][33] dwords

    const int tid   = threadIdx.x;
    const int wv    = tid >> 6;
    const int lane  = tid & 63;
    const int row16 = lane & 15;
    const int quad  = lane >> 4;
    const int h4    = wv & 3;
    const int seg   = wv >> 2;               // 0..3, 1024 j each

    const int bx   = blockIdx.x;             // 0..255
    const int hg   = (bx >> 3) & 1;
    const int tile = ((bx >> 4) << 3) | (bx & 7);   // 0..127, 32 rows each

    // ---- stage this tile's mask bits: 16 KB, all 1024 threads, one int4 each
    {
        int c  = tid >> 6;                   // row-pair chunk 0..15
        int o  = (tid & 63) * 16;            // byte offset in 1-KB chunk
        int4 v = *(const int4*)((const char*)maskp + (size_t)(tile * 16 + c) * 32768 + o);
        int r  = c * 2 + (o >> 9);
        int ob = o & 511;
        int s  = ob >> 7;
        int t0 = (ob & 127) >> 2;
        unsigned* d = &lmask[s * 1056 + r * 33 + t0];
        d[0] = v.x; d[1] = v.y; d[2] = v.z; d[3] = v.w;
    }
    __syncthreads();

    const int h   = hg * 4 + h4;
    const int i0  = tile * 32 + row16;
    const int i1  = i0 + 16;
    const int shl = quad * 8;

    const float si0 = srcv[h * NN + i0];
    const float si1 = srcv[h * NN + i1];
    const float Es0 = __expf(si0),          Es1 = __expf(si1);
    const float Fs0 = __expf(ALPHA * si0),  Fs1 = __expf(ALPHA * si1);
    const unsigned thr0 = __builtin_bit_cast(unsigned short, (__bf16)__expf(-si0));
    const unsigned thr1 = __builtin_bit_cast(unsigned short, (__bf16)__expf(-si1));

    const unsigned short* Eb = Ebf + h * NN + seg * 1024;
    const unsigned short* Fb = Fbf + h * NN + seg * 1024;
    const unsigned short* wh = WhT + (size_t)h * FOUT * NN + seg * 1024;
    const unsigned* lm0 = &lmask[seg * 1056 + row16 * 33];
    const unsigned* lm1 = &lmask[seg * 1056 + (row16 + 16) * 33];

    bf16x8 ones;
#pragma unroll
    for (int k = 0; k < 8; ++k) ones[k] = (__bf16)1.0f;

    f32x4 acc0[4] = {}, acc1[4] = {};
    f32x4 accl0 = {}, accl1 = {};

#pragma unroll 1
    for (int t = 0; t < 32; ++t) {
        int jj = t * 32 + shl;
        u16x8 ev = *(const u16x8*)(Eb + jj);
        u16x8 fv = *(const u16x8*)(Fb + jj);
        unsigned mb0 = (lm0[t] >> shl) & 0xffu;
        unsigned mb1 = (lm1[t] >> shl) & 0xffu;
        bf16x8 af0, af1;
#pragma unroll
        for (int k = 0; k < 8; ++k) {
            unsigned eu = ev[k], fu = fv[k];
            bool  g0 = eu >= thr0;
            float b0 = __uint_as_float((g0 ? eu : fu) << 16);
            float p0 = b0 * (g0 ? Es0 : Fs0);
            af0[k] = (__bf16)((mb0 >> k) & 1u ? p0 : 0.f);
            bool  g1 = eu >= thr1;
            float b1 = __uint_as_float((g1 ? eu : fu) << 16);
            float p1 = b1 * (g1 ? Es1 : Fs1);
            af1[k] = (__bf16)((mb1 >> k) & 1u ? p1 : 0.f);
        }
        bf16x8 b[4];
#pragma unroll
        for (int ot = 0; ot < 4; ++ot)
            b[ot] = *(const bf16x8*)(wh + (size_t)(ot * 16 + row16) * NN + jj);
#pragma unroll
        for (int ot = 0; ot < 4; ++ot) {
            acc0[ot] = __builtin_amdgcn_mfma_f32_16x16x32_bf16(af0, b[ot], acc0[ot], 0, 0, 0);
            acc1[ot] = __builtin_amdgcn_mfma_f32_16x16x32_bf16(af1, b[ot], acc1[ot], 0, 0, 0);
        }
        accl0 = __builtin_amdgcn_mfma_f32_16x16x32_bf16(af0, ones, accl0, 0, 0, 0);
        accl1 = __builtin_amdgcn_mfma_f32_16x16x32_bf16(af1, ones, accl1, 0, 0, 0);
    }

    __syncthreads();   // mask reads done; stash region may now be overwritten

    // ---- segment-combine tree in LDS ----
    if (seg == 1 || seg == 3) {
        int buf = (seg - 1) >> 1;
        float* st = &lds_stash[buf][h4][0];
#pragma unroll
        for (int ot = 0; ot < 4; ++ot)
#pragma unroll
            for (int r = 0; r < 4; ++r) {
                st[(quad * 4 + r) * 64 + ot * 16 + row16]      = acc0[ot][r];
                st[(16 + quad * 4 + r) * 64 + ot * 16 + row16] = acc1[ot][r];
            }
        if (row16 == 0) {
#pragma unroll
            for (int r = 0; r < 4; ++r) {
                lds_l[buf][h4][quad * 4 + r]      = accl0[r];
                lds_l[buf][h4][16 + quad * 4 + r] = accl1[r];
            }
        }
    }
    __syncthreads();
    if (seg == 0 || seg == 2) {
        int buf = seg >> 1;
        const float* st = &lds_stash[buf][h4][0];
#pragma unroll
        for (int ot = 0; ot < 4; ++ot)
#pragma unroll
            for (int r = 0; r < 4; ++r) {
                acc0[ot][r] += st[(quad * 4 + r) * 64 + ot * 16 + row16];
                acc1[ot][r] += st[(16 + quad * 4 + r) * 64 + ot * 16 + row16];
            }
#pragma unroll
        for (int r = 0; r < 4; ++r) {
            accl0[r] += lds_l[buf][h4][quad * 4 + r];
            accl1[r] += lds_l[buf][h4][16 + quad * 4 + r];
        }
    }
    __syncthreads();
    if (seg == 2) {
        float* st = &lds_stash[0][h4][0];
#pragma unroll
        for (int ot = 0; ot < 4; ++ot)
#pragma unroll
            for (int r = 0; r < 4; ++r) {
                st[(quad * 4 + r) * 64 + ot * 16 + row16]      = acc0[ot][r];
                st[(16 + quad * 4 + r) * 64 + ot * 16 + row16] = acc1[ot][r];
            }
        if (row16 == 0) {
#pragma unroll
            for (int r = 0; r < 4; ++r) {
                lds_l[0][h4][quad * 4 + r]      = accl0[r];
                lds_l[0][h4][16 + quad * 4 + r] = accl1[r];
            }
        }
    }
    __syncthreads();
    if (seg == 0) {
        const float* st = &lds_stash[0][h4][0];
#pragma unroll
        for (int r = 0; r < 4; ++r) {
            int qr = quad * 4 + r;
            float l0 = accl0[r] + lds_l[0][h4][qr];
            float l1 = accl1[r] + lds_l[0][h4][16 + qr];
            float rl0 = 1.0f / l0, rl1 = 1.0f / l1;
#pragma unroll
            for (int ot = 0; ot < 4; ++ot) {
                int c = ot * 16 + row16;
                float v0 = (acc0[ot][r] + st[qr * 64 + c]) * rl0;
                float v1 = (acc1[ot][r] + st[(16 + qr) * 64 + c]) * rl1;
                float y0 = v0 > 0.f ? v0 : __expf(v0) - 1.f;
                float y1 = v1 > 0.f ? v1 : __expf(v1) - 1.f;
                out[(size_t)(tile * 32 + qr) * (HH * FOUT) + h * FOUT + c]      = y0;
                out[(size_t)(tile * 32 + 16 + qr) * (HH * FOUT) + h * FOUT + c] = y1;
            }
        }
    }
}

// ---------------------------------------------------------------------------
extern "C" void kernel_launch(void* const* d_in, const int* in_sizes, int n_in,
                              void* d_out, int out_size, void* d_ws, size_t ws_size,
                              hipStream_t stream) {
    const float* features = (const float*)d_in[0];
    int*         adj      = (int*)d_in[1];     // packed in place by k_pack
    const float* W        = (const float*)d_in[2];
    const float* a_src    = (const float*)d_in[3];
    const float* a_dst    = (const float*)d_in[4];
    float*       out      = (float*)d_out;

    // Workspace: exactly the proven 4.75 MB footprint
    char* ws = (char*)d_ws;
    __hip_bfloat16* WT   = (__hip_bfloat16*)(ws);                             // 512 KB
    __hip_bfloat16* WhT  = (__hip_bfloat16*)(ws + (512 << 10));               // 4 MB
    float*          srcv = (float*)(ws + (512 << 10) + (4 << 20));            // 128 KB
    unsigned short* Ebf  = (unsigned short*)(ws + (512 << 10) + (4 << 20) + (128 << 10));  // 64 KB
    unsigned short* Fbf  = (unsigned short*)(ws + (512 << 10) + (4 << 20) + (192 << 10));  // 64 KB

    k_pack<<<dim3((NN * NN) / 8192), 256, 0, stream>>>(adj);
    k_transpose_w<<<dim3(64), 256, 0, stream>>>(W, WT);
    k_proj<<<dim3(NN / 16, 2), 256, 0, stream>>>(features, WT, a_src, a_dst,
                                                 WhT, srcv, Ebf, Fbf);
    k_flash<<<dim3(256), 1024, 0, stream>>>((const unsigned*)adj, srcv, Ebf, Fbf,
                                            (const unsigned short*)WhT, out);
}

// Round 10
// 176.047 us; speedup vs baseline: 1.7418x; 1.1153x over previous
//
#include <hip/hip_runtime.h>
#include <hip/hip_bf16.h>

typedef __bf16 bf16x8 __attribute__((ext_vector_type(8)));
typedef float  f32x4  __attribute__((ext_vector_type(4)));
typedef unsigned short u16x8 __attribute__((ext_vector_type(8)));
typedef unsigned short us4   __attribute__((ext_vector_type(4)));

#define HH    8
#define NN    4096
#define FIN   512
#define FOUT  64
#define ALPHA 0.2f

// ---------------------------------------------------------------------------
// k_pack: in-place adjacency bit-pack (64 MB -> 2 MB). Block b owns rows
// 2b,2b+1 (8192 ints) and rewrites the first 1 KB of its own 32768-B region
// as bits: bit j%32 of dword  b*8192 + (i&1)*128 + j/32  == adj[i][j] > 0.
// NOTE: packed bits are NOT contiguous across row-pairs — each pair's 1 KB
// sits at byte rp*32768 (rest of the region is stale adjacency).
// ---------------------------------------------------------------------------
__global__ __launch_bounds__(256) void k_pack(int* __restrict__ adj) {
    const size_t base = (size_t)blockIdx.x * 8192;
    const int    tid  = threadIdx.x;
    unsigned m = 0;
#pragma unroll
    for (int p = 0; p < 8; ++p) {
        int4 v = *(const int4*)(adj + base + tid * 32 + p * 4);
        m |= (unsigned)(v.x > 0) << (p * 4);
        m |= (unsigned)(v.y > 0) << (p * 4 + 1);
        m |= (unsigned)(v.z > 0) << (p * 4 + 2);
        m |= (unsigned)(v.w > 0) << (p * 4 + 3);
    }
    __syncthreads();
    ((unsigned*)adj)[base + tid] = m;
}

// ---------------------------------------------------------------------------
// k0: W[h][f][o] (fp32) -> WT[h][o][f] (bf16), coalesced via LDS 64x64 tile.
// ---------------------------------------------------------------------------
__global__ __launch_bounds__(256) void k_transpose_w(
    const float* __restrict__ Wsrc, __hip_bfloat16* __restrict__ WT) {
    __shared__ __hip_bfloat16 lt[64][65];
    const int h  = blockIdx.x >> 3;
    const int f0 = (blockIdx.x & 7) * 64;
    const int tid = threadIdx.x;
#pragma unroll
    for (int p = 0; p < 16; ++p) {
        int f = p * 4 + (tid >> 6);
        int o = tid & 63;
        lt[f][o] = __float2bfloat16(Wsrc[((size_t)h * FIN + f0 + f) * FOUT + o]);
    }
    __syncthreads();
#pragma unroll
    for (int p = 0; p < 16; ++p) {
        int o = p * 4 + (tid >> 6);
        int f = tid & 63;
        WT[((size_t)h * FOUT + o) * FIN + f0 + f] = lt[f][o];
    }
}

// ---------------------------------------------------------------------------
// k_proj: Wh = feat @ W[h] via bf16 MFMA, M=32 rows/wave (B loads amortized
// over 32 rows). Block = 256 thr = 4 waves = 4 heads; grid (128 tiles, 2 hg).
// Writes WhT[h][o][n] (bf16, packed ushort4 stores), srcv (fp32),
// Ebf[h][n]=bf16(exp(dst)), Fbf[h][n]=bf16(exp(0.2*dst)).
// ---------------------------------------------------------------------------
__global__ __launch_bounds__(256) void k_proj(
    const float* __restrict__ feat,
    const __hip_bfloat16* __restrict__ WT,
    const float* __restrict__ a_src,
    const float* __restrict__ a_dst,
    unsigned short* __restrict__ WhT,
    float* __restrict__ srcv,
    unsigned short* __restrict__ Ebf, unsigned short* __restrict__ Fbf) {
    __shared__ alignas(16) __hip_bfloat16 lfeat[32][520];

    const int tid  = threadIdx.x;
    const int tile = blockIdx.x;          // 32 rows per block

#pragma unroll
    for (int p = 0; p < 16; ++p) {
        int idx  = p * 256 + tid;         // 0..4095 float4s
        int row  = idx >> 7;
        int col4 = (idx & 127) * 4;
        float4 f = *(const float4*)(feat + (size_t)(tile * 32 + row) * FIN + col4);
        __hip_bfloat16* dst = &lfeat[row][col4];
        dst[0] = __float2bfloat16(f.x); dst[1] = __float2bfloat16(f.y);
        dst[2] = __float2bfloat16(f.z); dst[3] = __float2bfloat16(f.w);
    }
    __syncthreads();

    const int h     = blockIdx.y * 4 + (tid >> 6);
    const int lane  = tid & 63;
    const int row16 = lane & 15;
    const int quad  = lane >> 4;

    const unsigned short* WTu = (const unsigned short*)WT + (size_t)h * FOUT * FIN;

    f32x4 acc[2][4] = {};
    for (int k0 = 0; k0 < FIN; k0 += 32) {
        bf16x8 a0 = *(const bf16x8*)&lfeat[row16][k0 + quad * 8];
        bf16x8 a1 = *(const bf16x8*)&lfeat[16 + row16][k0 + quad * 8];
#pragma unroll
        for (int ot = 0; ot < 4; ++ot) {
            bf16x8 b = *(const bf16x8*)(WTu + (size_t)(ot * 16 + row16) * FIN + k0 + quad * 8);
            acc[0][ot] = __builtin_amdgcn_mfma_f32_16x16x32_bf16(a0, b, acc[0][ot], 0, 0, 0);
            acc[1][ot] = __builtin_amdgcn_mfma_f32_16x16x32_bf16(a1, b, acc[1][ot], 0, 0, 0);
        }
    }

    // WhT stores: 4 consecutive n per lane -> ushort4 (8 B)
#pragma unroll
    for (int g = 0; g < 2; ++g)
#pragma unroll
        for (int ot = 0; ot < 4; ++ot) {
            us4 u;
#pragma unroll
            for (int r = 0; r < 4; ++r)
                u[r] = __builtin_bit_cast(unsigned short, (__bf16)acc[g][ot][r]);
            *(us4*)(WhT + (size_t)(h * FOUT + ot * 16 + row16) * NN
                        + tile * 32 + g * 16 + quad * 4) = u;
        }

    float asv[4], adv[4];
#pragma unroll
    for (int ot = 0; ot < 4; ++ot) {
        asv[ot] = a_src[h * FOUT + ot * 16 + row16];
        adv[ot] = a_dst[h * FOUT + ot * 16 + row16];
    }
#pragma unroll
    for (int g = 0; g < 2; ++g)
#pragma unroll
        for (int r = 0; r < 4; ++r) {
            float ss = 0.f, dd = 0.f;
#pragma unroll
            for (int ot = 0; ot < 4; ++ot) {
                ss += acc[g][ot][r] * asv[ot];
                dd += acc[g][ot][r] * adv[ot];
            }
            ss += __shfl_xor(ss, 1); ss += __shfl_xor(ss, 2);
            ss += __shfl_xor(ss, 4); ss += __shfl_xor(ss, 8);
            dd += __shfl_xor(dd, 1); dd += __shfl_xor(dd, 2);
            dd += __shfl_xor(dd, 4); dd += __shfl_xor(dd, 8);
            if (row16 == 0) {
                int n = tile * 32 + g * 16 + quad * 4 + r;
                srcv[h * NN + n] = ss;
                __bf16 e = (__bf16)__expf(dd);
                __bf16 f = (__bf16)__expf(ALPHA * dd);
                Ebf[h * NN + n] = __builtin_bit_cast(unsigned short, e);
                Fbf[h * NN + n] = __builtin_bit_cast(unsigned short, f);
            }
        }
}

// ---------------------------------------------------------------------------
// k_flash: masked softmax attention + ELU. M=64 rows/wave.
// Governing law (R3..R8): ~60 cyc per global-vmem INSTRUCTION per CU;
// M=64 shares B + E/F loads across 4 row-groups.
// p = exp(LeakyReLU(s+d)) = max(Es*Ed, Fs*Fd)  (exp monotone, exact).
// Block = 512 thr = 8 waves = 2 heads x 4 j-segments; grid = 64 tiles x
// 4 hgroups = 256 blocks, swizzled: same-tile blocks share an XCD.
// Mask staged in LDS row-major [64 rows][132 dwords] (33 KB, unioned with
// the 64-KB stash). R9 FIX 1: stage per 1-KB row-pair chunk at byte
// (tile*32+c)*32768 (bits are NOT contiguous across pairs). R9 FIX 2:
// LDS read pointer includes + seg*32 dword offset.
// ---------------------------------------------------------------------------
__global__ __launch_bounds__(512, 2) void k_flash(
    const unsigned* __restrict__ maskp,      // packed bits (in adj buffer)
    const float* __restrict__ srcv,
    const unsigned short* __restrict__ Ebf,
    const unsigned short* __restrict__ Fbf,
    const unsigned short* __restrict__ WhT,  // [H][FOUT][NN] bf16 bits
    float* __restrict__ out) {
    __shared__ float lds_stash[2][2][4096];  // 64 KB; mask lives here in-loop
    __shared__ float lds_l[2][2][64];

    unsigned* lmask = (unsigned*)&lds_stash[0][0][0];   // [64 rows][132 dwords]

    const int tid   = threadIdx.x;
    const int wv    = tid >> 6;              // 0..7
    const int lane  = tid & 63;
    const int row16 = lane & 15;
    const int quad  = lane >> 4;
    const int h2    = wv & 1;                // local head
    const int seg   = wv >> 1;               // j-segment 0..3 (1024 j each)

    // swizzle: the 4 hgroup-blocks of one tile sit 8 apart -> same XCD slot
    const int bx   = blockIdx.x;             // 0..255
    const int hg   = (bx >> 3) & 3;
    const int tile = ((bx >> 5) << 3) | (bx & 7);   // 0..63, 64 rows each

    // ---- stage mask bits for 64 rows (32 row-pair chunks, 1 KB each)
#pragma unroll
    for (int p = 0; p < 4; ++p) {
        int tt = tid + p * 512;              // 0..2047 int4s
        int c  = tt >> 6;                    // row-pair chunk 0..31
        int o  = (tt & 63) * 16;             // byte offset within 1-KB chunk
        int4 v = *(const int4*)((const char*)maskp
                                + (size_t)(tile * 32 + c) * 32768 + o);
        int row = c * 2 + (o >> 9);          // 0..63
        int dw  = (o & 511) >> 2;            // dword within row, 0..127 (4-aligned)
        *(int4*)&lmask[row * 132 + dw] = v;
    }
    __syncthreads();

    const int h   = hg * 2 + h2;
    const int shl = quad * 8;

    float Es[4], Fs[4];
    const unsigned* lm[4];
#pragma unroll
    for (int g = 0; g < 4; ++g) {
        float si = srcv[h * NN + tile * 64 + g * 16 + row16];
        Es[g] = __expf(si);
        Fs[g] = __expf(ALPHA * si);
        lm[g] = &lmask[(g * 16 + row16) * 132 + seg * 32];
    }

    const unsigned short* Eb = Ebf + h * NN + seg * 1024;
    const unsigned short* Fb = Fbf + h * NN + seg * 1024;
    const unsigned short* wh = WhT + (size_t)h * FOUT * NN + seg * 1024;

    bf16x8 ones;
#pragma unroll
    for (int k = 0; k < 8; ++k) ones[k] = (__bf16)1.0f;

    f32x4 acc[4][4] = {};
    f32x4 accl[4]   = {};

#pragma unroll 1
    for (int t = 0; t < 32; ++t) {
        int jj = t * 32 + shl;
        u16x8 ev = *(const u16x8*)(Eb + jj);
        u16x8 fv = *(const u16x8*)(Fb + jj);
        unsigned mb[4];
#pragma unroll
        for (int g = 0; g < 4; ++g) mb[g] = (lm[g][t] >> shl) & 0xffu;

        bf16x8 af[4];
#pragma unroll
        for (int k = 0; k < 8; ++k) {
            float ef = __uint_as_float((unsigned)ev[k] << 16);
            float ff = __uint_as_float((unsigned)fv[k] << 16);
#pragma unroll
            for (int g = 0; g < 4; ++g) {
                float p = fmaxf(ef * Es[g], ff * Fs[g]);
                af[g][k] = (__bf16)(((mb[g] >> k) & 1u) ? p : 0.f);
            }
        }
        bf16x8 b[4];
#pragma unroll
        for (int ot = 0; ot < 4; ++ot)
            b[ot] = *(const bf16x8*)(wh + (size_t)(ot * 16 + row16) * NN + jj);
#pragma unroll
        for (int g = 0; g < 4; ++g) {
#pragma unroll
            for (int ot = 0; ot < 4; ++ot)
                acc[g][ot] = __builtin_amdgcn_mfma_f32_16x16x32_bf16(af[g], b[ot], acc[g][ot], 0, 0, 0);
            accl[g] = __builtin_amdgcn_mfma_f32_16x16x32_bf16(af[g], ones, accl[g], 0, 0, 0);
        }
    }

    __syncthreads();   // mask reads done; stash region may be overwritten

    // ---- segment-combine tree (per head): 1,3 stash; 0,2 add; 2 stash; 0 add
    if (seg == 1 || seg == 3) {
        float* st = &lds_stash[seg >> 1][h2][0];
#pragma unroll
        for (int g = 0; g < 4; ++g)
#pragma unroll
            for (int ot = 0; ot < 4; ++ot)
#pragma unroll
                for (int r = 0; r < 4; ++r)
                    st[(g * 16 + quad * 4 + r) * 64 + ot * 16 + row16] = acc[g][ot][r];
        if (row16 == 0)
#pragma unroll
            for (int g = 0; g < 4; ++g)
#pragma unroll
                for (int r = 0; r < 4; ++r)
                    lds_l[seg >> 1][h2][g * 16 + quad * 4 + r] = accl[g][r];
    }
    __syncthreads();
    if (seg == 0 || seg == 2) {
        const float* st = &lds_stash[seg >> 1][h2][0];
#pragma unroll
        for (int g = 0; g < 4; ++g) {
#pragma unroll
            for (int ot = 0; ot < 4; ++ot)
#pragma unroll
                for (int r = 0; r < 4; ++r)
                    acc[g][ot][r] += st[(g * 16 + quad * 4 + r) * 64 + ot * 16 + row16];
#pragma unroll
            for (int r = 0; r < 4; ++r)
                accl[g][r] += lds_l[seg >> 1][h2][g * 16 + quad * 4 + r];
        }
    }
    __syncthreads();
    if (seg == 2) {
        float* st = &lds_stash[0][h2][0];
#pragma unroll
        for (int g = 0; g < 4; ++g)
#pragma unroll
            for (int ot = 0; ot < 4; ++ot)
#pragma unroll
                for (int r = 0; r < 4; ++r)
                    st[(g * 16 + quad * 4 + r) * 64 + ot * 16 + row16] = acc[g][ot][r];
        if (row16 == 0)
#pragma unroll
            for (int g = 0; g < 4; ++g)
#pragma unroll
                for (int r = 0; r < 4; ++r)
                    lds_l[0][h2][g * 16 + quad * 4 + r] = accl[g][r];
    }
    __syncthreads();
    if (seg == 0) {
        const float* st = &lds_stash[0][h2][0];
#pragma unroll
        for (int g = 0; g < 4; ++g)
#pragma unroll
            for (int r = 0; r < 4; ++r) {
                int   gqr = g * 16 + quad * 4 + r;
                float l   = accl[g][r] + lds_l[0][h2][gqr];
                float rl  = 1.0f / l;
#pragma unroll
                for (int ot = 0; ot < 4; ++ot) {
                    int   c = ot * 16 + row16;
                    float v = (acc[g][ot][r] + st[gqr * 64 + c]) * rl;
                    float y = v > 0.f ? v : __expf(v) - 1.f;  // ELU
                    out[(size_t)(tile * 64 + gqr) * (HH * FOUT) + h * FOUT + c] = y;
                }
            }
    }
}

// ---------------------------------------------------------------------------
extern "C" void kernel_launch(void* const* d_in, const int* in_sizes, int n_in,
                              void* d_out, int out_size, void* d_ws, size_t ws_size,
                              hipStream_t stream) {
    const float* features = (const float*)d_in[0];
    int*         adj      = (int*)d_in[1];     // packed in place by k_pack
    const float* W        = (const float*)d_in[2];
    const float* a_src    = (const float*)d_in[3];
    const float* a_dst    = (const float*)d_in[4];
    float*       out      = (float*)d_out;

    // Workspace: exactly the proven 4.75 MB footprint
    char* ws = (char*)d_ws;
    __hip_bfloat16* WT   = (__hip_bfloat16*)(ws);                             // 512 KB
    unsigned short* WhT  = (unsigned short*)(ws + (512 << 10));               // 4 MB
    float*          srcv = (float*)(ws + (512 << 10) + (4 << 20));            // 128 KB
    unsigned short* Ebf  = (unsigned short*)(ws + (512 << 10) + (4 << 20) + (128 << 10));  // 64 KB
    unsigned short* Fbf  = (unsigned short*)(ws + (512 << 10) + (4 << 20) + (192 << 10));  // 64 KB

    k_pack<<<dim3((NN * NN) / 8192), 256, 0, stream>>>(adj);
    k_transpose_w<<<dim3(64), 256, 0, stream>>>(W, WT);
    k_proj<<<dim3(NN / 32, 2), 256, 0, stream>>>(features, WT, a_src, a_dst,
                                                 WhT, srcv, Ebf, Fbf);
    k_flash<<<dim3(256), 512, 0, stream>>>((const unsigned*)adj, srcv, Ebf, Fbf,
                                           WhT, out);
}

// Round 11
// 174.697 us; speedup vs baseline: 1.7552x; 1.0077x over previous
//
#include <hip/hip_runtime.h>
#include <hip/hip_bf16.h>

typedef __bf16 bf16x8 __attribute__((ext_vector_type(8)));
typedef float  f32x4  __attribute__((ext_vector_type(4)));
typedef unsigned short u16x8 __attribute__((ext_vector_type(8)));
typedef unsigned short us4   __attribute__((ext_vector_type(4)));

#define HH    8
#define NN    4096
#define FIN   512
#define FOUT  64
#define ALPHA 0.2f

// ---------------------------------------------------------------------------
// k0: W[h][f][o] (fp32) -> WT[h][o][f] (bf16), coalesced via LDS 64x64 tile.
// ---------------------------------------------------------------------------
__global__ __launch_bounds__(256) void k_transpose_w(
    const float* __restrict__ Wsrc, __hip_bfloat16* __restrict__ WT) {
    __shared__ __hip_bfloat16 lt[64][65];
    const int h  = blockIdx.x >> 3;
    const int f0 = (blockIdx.x & 7) * 64;
    const int tid = threadIdx.x;
#pragma unroll
    for (int p = 0; p < 16; ++p) {
        int f = p * 4 + (tid >> 6);
        int o = tid & 63;
        lt[f][o] = __float2bfloat16(Wsrc[((size_t)h * FIN + f0 + f) * FOUT + o]);
    }
    __syncthreads();
#pragma unroll
    for (int p = 0; p < 16; ++p) {
        int o = p * 4 + (tid >> 6);
        int f = tid & 63;
        WT[((size_t)h * FOUT + o) * FIN + f0 + f] = lt[f][o];
    }
}

// ---------------------------------------------------------------------------
// k_prep: FUSED adjacency bit-pack + projection (independent work; one launch).
// Blocks [0,2048): in-place pack — block b owns rows 2b,2b+1 (8192 ints),
//   rewrites first 1 KB of its 32768-B region as bits (bits NOT contiguous
//   across row-pairs). Within-block write-after-read, __syncthreads-guarded.
// Blocks [2048,2304): projection, pb = bx-2048: tile = pb&127 (32 rows),
//   hgroup = pb>>7; 4 waves = 4 heads. Writes WhT[h][o][n] bf16 (ushort4),
//   srcv fp32, Ebf=bf16(exp(dst)), Fbf=bf16(exp(0.2*dst)).
// ---------------------------------------------------------------------------
__global__ __launch_bounds__(256) void k_prep(
    int* __restrict__ adj,
    const float* __restrict__ feat,
    const __hip_bfloat16* __restrict__ WT,
    const float* __restrict__ a_src,
    const float* __restrict__ a_dst,
    unsigned short* __restrict__ WhT,
    float* __restrict__ srcv,
    unsigned short* __restrict__ Ebf, unsigned short* __restrict__ Fbf) {
    __shared__ alignas(16) __hip_bfloat16 lfeat[32][520];

    const int tid = threadIdx.x;

    if (blockIdx.x < 2048) {   // ---- pack path ----
        const size_t base = (size_t)blockIdx.x * 8192;
        unsigned m = 0;
#pragma unroll
        for (int p = 0; p < 8; ++p) {
            int4 v = *(const int4*)(adj + base + tid * 32 + p * 4);
            m |= (unsigned)(v.x > 0) << (p * 4);
            m |= (unsigned)(v.y > 0) << (p * 4 + 1);
            m |= (unsigned)(v.z > 0) << (p * 4 + 2);
            m |= (unsigned)(v.w > 0) << (p * 4 + 3);
        }
        __syncthreads();
        ((unsigned*)adj)[base + tid] = m;
        return;
    }

    // ---- projection path ----
    const int pb   = blockIdx.x - 2048;
    const int tile = pb & 127;            // 32 rows per block
    const int hgy  = pb >> 7;             // 0..1

#pragma unroll
    for (int p = 0; p < 16; ++p) {
        int idx  = p * 256 + tid;         // 0..4095 float4s
        int row  = idx >> 7;
        int col4 = (idx & 127) * 4;
        float4 f = *(const float4*)(feat + (size_t)(tile * 32 + row) * FIN + col4);
        __hip_bfloat16* dst = &lfeat[row][col4];
        dst[0] = __float2bfloat16(f.x); dst[1] = __float2bfloat16(f.y);
        dst[2] = __float2bfloat16(f.z); dst[3] = __float2bfloat16(f.w);
    }
    __syncthreads();

    const int h     = hgy * 4 + (tid >> 6);
    const int lane  = tid & 63;
    const int row16 = lane & 15;
    const int quad  = lane >> 4;

    const unsigned short* WTu = (const unsigned short*)WT + (size_t)h * FOUT * FIN;

    f32x4 acc[2][4] = {};
    for (int k0 = 0; k0 < FIN; k0 += 32) {
        bf16x8 a0 = *(const bf16x8*)&lfeat[row16][k0 + quad * 8];
        bf16x8 a1 = *(const bf16x8*)&lfeat[16 + row16][k0 + quad * 8];
#pragma unroll
        for (int ot = 0; ot < 4; ++ot) {
            bf16x8 b = *(const bf16x8*)(WTu + (size_t)(ot * 16 + row16) * FIN + k0 + quad * 8);
            acc[0][ot] = __builtin_amdgcn_mfma_f32_16x16x32_bf16(a0, b, acc[0][ot], 0, 0, 0);
            acc[1][ot] = __builtin_amdgcn_mfma_f32_16x16x32_bf16(a1, b, acc[1][ot], 0, 0, 0);
        }
    }

#pragma unroll
    for (int g = 0; g < 2; ++g)
#pragma unroll
        for (int ot = 0; ot < 4; ++ot) {
            us4 u;
#pragma unroll
            for (int r = 0; r < 4; ++r)
                u[r] = __builtin_bit_cast(unsigned short, (__bf16)acc[g][ot][r]);
            *(us4*)(WhT + (size_t)(h * FOUT + ot * 16 + row16) * NN
                        + tile * 32 + g * 16 + quad * 4) = u;
        }

    float asv[4], adv[4];
#pragma unroll
    for (int ot = 0; ot < 4; ++ot) {
        asv[ot] = a_src[h * FOUT + ot * 16 + row16];
        adv[ot] = a_dst[h * FOUT + ot * 16 + row16];
    }
#pragma unroll
    for (int g = 0; g < 2; ++g)
#pragma unroll
        for (int r = 0; r < 4; ++r) {
            float ss = 0.f, dd = 0.f;
#pragma unroll
            for (int ot = 0; ot < 4; ++ot) {
                ss += acc[g][ot][r] * asv[ot];
                dd += acc[g][ot][r] * adv[ot];
            }
            ss += __shfl_xor(ss, 1); ss += __shfl_xor(ss, 2);
            ss += __shfl_xor(ss, 4); ss += __shfl_xor(ss, 8);
            dd += __shfl_xor(dd, 1); dd += __shfl_xor(dd, 2);
            dd += __shfl_xor(dd, 4); dd += __shfl_xor(dd, 8);
            if (row16 == 0) {
                int n = tile * 32 + g * 16 + quad * 4 + r;
                srcv[h * NN + n] = ss;
                __bf16 e = (__bf16)__expf(dd);
                __bf16 f = (__bf16)__expf(ALPHA * dd);
                Ebf[h * NN + n] = __builtin_bit_cast(unsigned short, e);
                Fbf[h * NN + n] = __builtin_bit_cast(unsigned short, f);
            }
        }
}

// ---------------------------------------------------------------------------
// k_flash: masked softmax attention + ELU. M=128 rows/wave.
// Law (R3..R10): ~60 cyc per global-vmem instruction per CU + ~31 µs VALU
// floor, nearly additive at low occupancy. M=128 halves vmem instr per score
// vs R10 (6 instr now cover 128 rows x 32 j). VALU unchanged (per-score).
// Block = 512 thr = 8 waves = 1 head x 8 j-segments (512 j, 16 iters);
// grid dim3(32 tiles, 8 heads): flat%8 = bx%8 -> all 8 same-tile blocks on
// one XCD (mask L2 locality, free). p = max(Es*Ed, Fs*Fd) (exact).
// Mask: 128 rows x 132 dwords in LDS (67.6 KB), unioned with 2 stash bufs
// (stride 68 -> 2-way banks only). 8-seg pairwise combine tree; epilogue
// through LDS -> coalesced float4 stores.
// ---------------------------------------------------------------------------
__global__ __launch_bounds__(512, 2) void k_flash(
    const unsigned* __restrict__ maskp,
    const float* __restrict__ srcv,
    const unsigned short* __restrict__ Ebf,
    const unsigned short* __restrict__ Fbf,
    const unsigned short* __restrict__ WhT,
    float* __restrict__ out) {
    __shared__ float st[2][128 * 68];    // 69632 B; mask aliases st during loop
    __shared__ float lds_l[2][128];

    unsigned* lmask = (unsigned*)&st[0][0];   // [128 rows][132 dwords]

    const int tid   = threadIdx.x;
    const int seg   = tid >> 6;               // 0..7, 512 j each
    const int lane  = tid & 63;
    const int row16 = lane & 15;
    const int quad  = lane >> 4;
    const int shl   = quad * 8;
    const int tile  = blockIdx.x;             // 128 rows
    const int h     = blockIdx.y;

    // ---- stage mask bits for 128 rows (64 row-pair chunks, 1 KB each)
#pragma unroll
    for (int p = 0; p < 8; ++p) {
        int tt = tid + p * 512;               // 0..4095 int4s
        int c  = tt >> 6;                     // chunk 0..63
        int o  = (tt & 63) * 16;              // byte in chunk
        int4 v = *(const int4*)((const char*)maskp
                                + (size_t)(tile * 64 + c) * 32768 + o);
        int row = c * 2 + (o >> 9);
        int dw  = (o & 511) >> 2;
        *(int4*)&lmask[row * 132 + dw] = v;
    }
    __syncthreads();

    float Es[8], Fs[8];
#pragma unroll
    for (int g = 0; g < 8; ++g) {
        float si = srcv[h * NN + tile * 128 + g * 16 + row16];
        Es[g] = __expf(si);
        Fs[g] = __expf(ALPHA * si);
    }
    const int mbase = row16 * 132 + seg * 16;   // + g*2112 + t

    const unsigned short* Eb = Ebf + h * NN + seg * 512;
    const unsigned short* Fb = Fbf + h * NN + seg * 512;
    const unsigned short* wh = WhT + (size_t)h * FOUT * NN + seg * 512;

    bf16x8 ones;
#pragma unroll
    for (int k = 0; k < 8; ++k) ones[k] = (__bf16)1.0f;

    f32x4 acc[8][4] = {};
    f32x4 accl[8]   = {};

#pragma unroll 1
    for (int t = 0; t < 16; ++t) {
        int jj = t * 32 + shl;
        u16x8 ev = *(const u16x8*)(Eb + jj);
        u16x8 fv = *(const u16x8*)(Fb + jj);
        bf16x8 b[4];
#pragma unroll
        for (int ot = 0; ot < 4; ++ot)
            b[ot] = *(const bf16x8*)(wh + (size_t)(ot * 16 + row16) * NN + jj);

        float ef[8], ff[8];
#pragma unroll
        for (int k = 0; k < 8; ++k) {
            ef[k] = __uint_as_float((unsigned)ev[k] << 16);
            ff[k] = __uint_as_float((unsigned)fv[k] << 16);
        }

#pragma unroll
        for (int gp = 0; gp < 4; ++gp) {      // g in pairs: caps live af regs
            const int g0 = gp * 2, g1 = g0 + 1;
            unsigned mb0 = (lmask[mbase + g0 * 2112 + t] >> shl) & 0xffu;
            unsigned mb1 = (lmask[mbase + g1 * 2112 + t] >> shl) & 0xffu;
            bf16x8 af0, af1;
#pragma unroll
            for (int k = 0; k < 8; ++k) {
                float p0 = fmaxf(ef[k] * Es[g0], ff[k] * Fs[g0]);
                float p1 = fmaxf(ef[k] * Es[g1], ff[k] * Fs[g1]);
                af0[k] = (__bf16)(((mb0 >> k) & 1u) ? p0 : 0.f);
                af1[k] = (__bf16)(((mb1 >> k) & 1u) ? p1 : 0.f);
            }
#pragma unroll
            for (int ot = 0; ot < 4; ++ot) {
                acc[g0][ot] = __builtin_amdgcn_mfma_f32_16x16x32_bf16(af0, b[ot], acc[g0][ot], 0, 0, 0);
                acc[g1][ot] = __builtin_amdgcn_mfma_f32_16x16x32_bf16(af1, b[ot], acc[g1][ot], 0, 0, 0);
            }
            accl[g0] = __builtin_amdgcn_mfma_f32_16x16x32_bf16(af0, ones, accl[g0], 0, 0, 0);
            accl[g1] = __builtin_amdgcn_mfma_f32_16x16x32_bf16(af1, ones, accl[g1], 0, 0, 0);
        }
    }

    __syncthreads();   // mask reads done; st[] may be reused as stash

    // stash/addin helpers over [128 rows][68-stride] layout
    auto stash = [&](int buf) {
#pragma unroll
        for (int g = 0; g < 8; ++g)
#pragma unroll
            for (int ot = 0; ot < 4; ++ot)
#pragma unroll
                for (int r = 0; r < 4; ++r)
                    st[buf][(g * 16 + quad * 4 + r) * 68 + ot * 16 + row16] = acc[g][ot][r];
        if (row16 == 0)
#pragma unroll
            for (int g = 0; g < 8; ++g)
#pragma unroll
                for (int r = 0; r < 4; ++r)
                    lds_l[buf][g * 16 + quad * 4 + r] = accl[g][r];
    };
    auto addin = [&](int buf) {
#pragma unroll
        for (int g = 0; g < 8; ++g) {
#pragma unroll
            for (int ot = 0; ot < 4; ++ot)
#pragma unroll
                for (int r = 0; r < 4; ++r)
                    acc[g][ot][r] += st[buf][(g * 16 + quad * 4 + r) * 68 + ot * 16 + row16];
#pragma unroll
            for (int r = 0; r < 4; ++r)
                accl[g][r] += lds_l[buf][g * 16 + quad * 4 + r];
        }
    };

    if (seg == 1) stash(0);
    if (seg == 3) stash(1);
    __syncthreads();
    if (seg == 0) addin(0);
    if (seg == 2) addin(1);
    __syncthreads();
    if (seg == 5) stash(0);
    if (seg == 7) stash(1);
    __syncthreads();
    if (seg == 4) addin(0);
    if (seg == 6) addin(1);
    __syncthreads();
    if (seg == 2) stash(0);
    if (seg == 6) stash(1);
    __syncthreads();
    if (seg == 0) addin(0);
    if (seg == 4) addin(1);
    __syncthreads();
    if (seg == 4) stash(0);
    __syncthreads();
    if (seg == 0) {
        addin(0);
        // epilogue: divide by l, ELU, deposit final tile into st[0][row][col]
#pragma unroll
        for (int g = 0; g < 8; ++g)
#pragma unroll
            for (int r = 0; r < 4; ++r) {
                int   gqr = g * 16 + quad * 4 + r;
                float rl  = 1.0f / accl[g][r];
#pragma unroll
                for (int ot = 0; ot < 4; ++ot) {
                    float v = acc[g][ot][r] * rl;
                    float y = v > 0.f ? v : __expf(v) - 1.f;
                    st[0][gqr * 68 + ot * 16 + row16] = y;
                }
            }
    }
    __syncthreads();
    // cooperative coalesced store: 2048 float4s by 512 threads
#pragma unroll
    for (int p = 0; p < 4; ++p) {
        int f    = tid + p * 512;             // 0..2047
        int row  = f >> 4;
        int col4 = (f & 15) * 4;
        float4 v = *(const float4*)&st[0][row * 68 + col4];
        *(float4*)&out[(size_t)(tile * 128 + row) * (HH * FOUT) + h * FOUT + col4] = v;
    }
}

// ---------------------------------------------------------------------------
extern "C" void kernel_launch(void* const* d_in, const int* in_sizes, int n_in,
                              void* d_out, int out_size, void* d_ws, size_t ws_size,
                              hipStream_t stream) {
    const float* features = (const float*)d_in[0];
    int*         adj      = (int*)d_in[1];     // packed in place by k_prep
    const float* W        = (const float*)d_in[2];
    const float* a_src    = (const float*)d_in[3];
    const float* a_dst    = (const float*)d_in[4];
    float*       out      = (float*)d_out;

    // Workspace: exactly the proven 4.75 MB footprint
    char* ws = (char*)d_ws;
    __hip_bfloat16* WT   = (__hip_bfloat16*)(ws);                             // 512 KB
    unsigned short* WhT  = (unsigned short*)(ws + (512 << 10));               // 4 MB
    float*          srcv = (float*)(ws + (512 << 10) + (4 << 20));            // 128 KB
    unsigned short* Ebf  = (unsigned short*)(ws + (512 << 10) + (4 << 20) + (128 << 10));  // 64 KB
    unsigned short* Fbf  = (unsigned short*)(ws + (512 << 10) + (4 << 20) + (192 << 10));  // 64 KB

    k_transpose_w<<<dim3(64), 256, 0, stream>>>(W, WT);
    k_prep<<<dim3(2048 + 256), 256, 0, stream>>>(adj, features, WT, a_src, a_dst,
                                                 WhT, srcv, Ebf, Fbf);
    k_flash<<<dim3(32, 8), 512, 0, stream>>>((const unsigned*)adj, srcv, Ebf, Fbf,
                                             WhT, out);
}

// Round 12
// 169.485 us; speedup vs baseline: 1.8092x; 1.0308x over previous
//
#include <hip/hip_runtime.h>
#include <hip/hip_bf16.h>

typedef __bf16 bf16x8 __attribute__((ext_vector_type(8)));
typedef float  f32x4  __attribute__((ext_vector_type(4)));
typedef unsigned short u16x8 __attribute__((ext_vector_type(8)));
typedef unsigned short us4   __attribute__((ext_vector_type(4)));

#define HH    8
#define NN    4096
#define FIN   512
#define FOUT  64
#define ALPHA 0.2f

// ---------------------------------------------------------------------------
// k0: W[h][f][o] (fp32) -> WT[h][o][f] (bf16), coalesced via LDS 64x64 tile.
// ---------------------------------------------------------------------------
__global__ __launch_bounds__(256) void k_transpose_w(
    const float* __restrict__ Wsrc, __hip_bfloat16* __restrict__ WT) {
    __shared__ __hip_bfloat16 lt[64][65];
    const int h  = blockIdx.x >> 3;
    const int f0 = (blockIdx.x & 7) * 64;
    const int tid = threadIdx.x;
#pragma unroll
    for (int p = 0; p < 16; ++p) {
        int f = p * 4 + (tid >> 6);
        int o = tid & 63;
        lt[f][o] = __float2bfloat16(Wsrc[((size_t)h * FIN + f0 + f) * FOUT + o]);
    }
    __syncthreads();
#pragma unroll
    for (int p = 0; p < 16; ++p) {
        int o = p * 4 + (tid >> 6);
        int f = tid & 63;
        WT[((size_t)h * FOUT + o) * FIN + f0 + f] = lt[f][o];
    }
}

// ---------------------------------------------------------------------------
// k_prep: FUSED adjacency bit-pack + projection (independent work).
// Blocks [0,2048): in-place pack — block b owns rows 2b,2b+1; first 1 KB of
//   its 32768-B region becomes bits (NOT contiguous across row-pairs).
// Blocks [2048,2304): projection: tile = pb&127 (32 rows), hgroup = pb>>7.
// ---------------------------------------------------------------------------
__global__ __launch_bounds__(256) void k_prep(
    int* __restrict__ adj,
    const float* __restrict__ feat,
    const __hip_bfloat16* __restrict__ WT,
    const float* __restrict__ a_src,
    const float* __restrict__ a_dst,
    unsigned short* __restrict__ WhT,
    float* __restrict__ srcv,
    unsigned short* __restrict__ Ebf, unsigned short* __restrict__ Fbf) {
    __shared__ alignas(16) __hip_bfloat16 lfeat[32][520];

    const int tid = threadIdx.x;

    if (blockIdx.x < 2048) {   // ---- pack path ----
        const size_t base = (size_t)blockIdx.x * 8192;
        unsigned m = 0;
#pragma unroll
        for (int p = 0; p < 8; ++p) {
            int4 v = *(const int4*)(adj + base + tid * 32 + p * 4);
            m |= (unsigned)(v.x > 0) << (p * 4);
            m |= (unsigned)(v.y > 0) << (p * 4 + 1);
            m |= (unsigned)(v.z > 0) << (p * 4 + 2);
            m |= (unsigned)(v.w > 0) << (p * 4 + 3);
        }
        __syncthreads();
        ((unsigned*)adj)[base + tid] = m;
        return;
    }

    // ---- projection path ----
    const int pb   = blockIdx.x - 2048;
    const int tile = pb & 127;            // 32 rows per block
    const int hgy  = pb >> 7;             // 0..1

#pragma unroll
    for (int p = 0; p < 16; ++p) {
        int idx  = p * 256 + tid;
        int row  = idx >> 7;
        int col4 = (idx & 127) * 4;
        float4 f = *(const float4*)(feat + (size_t)(tile * 32 + row) * FIN + col4);
        __hip_bfloat16* dst = &lfeat[row][col4];
        dst[0] = __float2bfloat16(f.x); dst[1] = __float2bfloat16(f.y);
        dst[2] = __float2bfloat16(f.z); dst[3] = __float2bfloat16(f.w);
    }
    __syncthreads();

    const int h     = hgy * 4 + (tid >> 6);
    const int lane  = tid & 63;
    const int row16 = lane & 15;
    const int quad  = lane >> 4;

    const unsigned short* WTu = (const unsigned short*)WT + (size_t)h * FOUT * FIN;

    f32x4 acc[2][4] = {};
    for (int k0 = 0; k0 < FIN; k0 += 32) {
        bf16x8 a0 = *(const bf16x8*)&lfeat[row16][k0 + quad * 8];
        bf16x8 a1 = *(const bf16x8*)&lfeat[16 + row16][k0 + quad * 8];
#pragma unroll
        for (int ot = 0; ot < 4; ++ot) {
            bf16x8 b = *(const bf16x8*)(WTu + (size_t)(ot * 16 + row16) * FIN + k0 + quad * 8);
            acc[0][ot] = __builtin_amdgcn_mfma_f32_16x16x32_bf16(a0, b, acc[0][ot], 0, 0, 0);
            acc[1][ot] = __builtin_amdgcn_mfma_f32_16x16x32_bf16(a1, b, acc[1][ot], 0, 0, 0);
        }
    }

#pragma unroll
    for (int g = 0; g < 2; ++g)
#pragma unroll
        for (int ot = 0; ot < 4; ++ot) {
            us4 u;
#pragma unroll
            for (int r = 0; r < 4; ++r)
                u[r] = __builtin_bit_cast(unsigned short, (__bf16)acc[g][ot][r]);
            *(us4*)(WhT + (size_t)(h * FOUT + ot * 16 + row16) * NN
                        + tile * 32 + g * 16 + quad * 4) = u;
        }

    float asv[4], adv[4];
#pragma unroll
    for (int ot = 0; ot < 4; ++ot) {
        asv[ot] = a_src[h * FOUT + ot * 16 + row16];
        adv[ot] = a_dst[h * FOUT + ot * 16 + row16];
    }
#pragma unroll
    for (int g = 0; g < 2; ++g)
#pragma unroll
        for (int r = 0; r < 4; ++r) {
            float ss = 0.f, dd = 0.f;
#pragma unroll
            for (int ot = 0; ot < 4; ++ot) {
                ss += acc[g][ot][r] * asv[ot];
                dd += acc[g][ot][r] * adv[ot];
            }
            ss += __shfl_xor(ss, 1); ss += __shfl_xor(ss, 2);
            ss += __shfl_xor(ss, 4); ss += __shfl_xor(ss, 8);
            dd += __shfl_xor(dd, 1); dd += __shfl_xor(dd, 2);
            dd += __shfl_xor(dd, 4); dd += __shfl_xor(dd, 8);
            if (row16 == 0) {
                int n = tile * 32 + g * 16 + quad * 4 + r;
                srcv[h * NN + n] = ss;
                __bf16 e = (__bf16)__expf(dd);
                __bf16 f = (__bf16)__expf(ALPHA * dd);
                Ebf[h * NN + n] = __builtin_bit_cast(unsigned short, e);
                Fbf[h * NN + n] = __builtin_bit_cast(unsigned short, f);
            }
        }
}

// ---------------------------------------------------------------------------
// k_flash: masked softmax attention + ELU. M=128 rows/wave, j-split 8.
// R11 lesson: acc(128 AGPR) + accl ones-MFMA (32 AGPR) + 128 VGPR = 288 regs
// -> 1 wave/SIMD -> VALU (30 µs) and vmem (19 µs) serialize. Fix: drop the
// ones-MFMA; accumulate l in VALU from the pre-rounded masked p (+1 add/score,
// -8 MFMA/iter, -32 AGPR) -> ~230 regs -> 2 waves/SIMD -> pipes overlap.
// p = exp(LeakyReLU(s+d)) = max(Es*Ed, Fs*Fd) (exp monotone, exact).
// af packed via __float22bfloat162_rn on score pairs (pk-cvt codegen chance).
// Block = 512 thr = 8 waves = 1 head x 8 j-segs (512 j, 16 iters);
// grid dim3(32,8): all 8 same-tile blocks on one XCD. Mask: 128 rows x 132
// dwords in LDS (67.6 KB) unioned with 2 stash bufs (stride 68).
// ---------------------------------------------------------------------------
__global__ __launch_bounds__(512, 2) void k_flash(
    const unsigned* __restrict__ maskp,
    const float* __restrict__ srcv,
    const unsigned short* __restrict__ Ebf,
    const unsigned short* __restrict__ Fbf,
    const unsigned short* __restrict__ WhT,
    float* __restrict__ out) {
    __shared__ float st[2][128 * 68];    // 69632 B; mask aliases st during loop
    __shared__ float lds_l[2][128];

    unsigned* lmask = (unsigned*)&st[0][0];   // [128 rows][132 dwords]

    const int tid   = threadIdx.x;
    const int seg   = tid >> 6;               // 0..7, 512 j each
    const int lane  = tid & 63;
    const int row16 = lane & 15;
    const int quad  = lane >> 4;
    const int shl   = quad * 8;
    const int tile  = blockIdx.x;             // 128 rows
    const int h     = blockIdx.y;

    // ---- stage mask bits for 128 rows (64 row-pair chunks, 1 KB each)
#pragma unroll
    for (int p = 0; p < 8; ++p) {
        int tt = tid + p * 512;
        int c  = tt >> 6;
        int o  = (tt & 63) * 16;
        int4 v = *(const int4*)((const char*)maskp
                                + (size_t)(tile * 64 + c) * 32768 + o);
        int row = c * 2 + (o >> 9);
        int dw  = (o & 511) >> 2;
        *(int4*)&lmask[row * 132 + dw] = v;
    }
    __syncthreads();

    float Es[8], Fs[8];
#pragma unroll
    for (int g = 0; g < 8; ++g) {
        float si = srcv[h * NN + tile * 128 + g * 16 + row16];
        Es[g] = __expf(si);
        Fs[g] = __expf(ALPHA * si);
    }
    const int mbase = row16 * 132 + seg * 16;   // + g*2112 + t

    const unsigned short* Eb = Ebf + h * NN + seg * 512;
    const unsigned short* Fb = Fbf + h * NN + seg * 512;
    const unsigned short* wh = WhT + (size_t)h * FOUT * NN + seg * 512;

    f32x4 acc[8][4] = {};
    float lsum[8]   = {};

#pragma unroll 1
    for (int t = 0; t < 16; ++t) {
        int jj = t * 32 + shl;
        u16x8 ev = *(const u16x8*)(Eb + jj);
        u16x8 fv = *(const u16x8*)(Fb + jj);
        bf16x8 b[4];
#pragma unroll
        for (int ot = 0; ot < 4; ++ot)
            b[ot] = *(const bf16x8*)(wh + (size_t)(ot * 16 + row16) * NN + jj);

        float ef[8], ff[8];
#pragma unroll
        for (int k = 0; k < 8; ++k) {
            ef[k] = __uint_as_float((unsigned)ev[k] << 16);
            ff[k] = __uint_as_float((unsigned)fv[k] << 16);
        }

#pragma unroll
        for (int gp = 0; gp < 4; ++gp) {      // g in pairs: caps live af regs
            const int g0 = gp * 2, g1 = g0 + 1;
            unsigned mb0 = (lmask[mbase + g0 * 2112 + t] >> shl) & 0xffu;
            unsigned mb1 = (lmask[mbase + g1 * 2112 + t] >> shl) & 0xffu;
            union { bf16x8 v8; __hip_bfloat162 h2[4]; } a0u, a1u;
#pragma unroll
            for (int kk = 0; kk < 4; ++kk) {
                const int ka = kk * 2, kb = ka + 1;
                float p0a = ((mb0 >> ka) & 1u) ? fmaxf(ef[ka] * Es[g0], ff[ka] * Fs[g0]) : 0.f;
                float p0b = ((mb0 >> kb) & 1u) ? fmaxf(ef[kb] * Es[g0], ff[kb] * Fs[g0]) : 0.f;
                float p1a = ((mb1 >> ka) & 1u) ? fmaxf(ef[ka] * Es[g1], ff[ka] * Fs[g1]) : 0.f;
                float p1b = ((mb1 >> kb) & 1u) ? fmaxf(ef[kb] * Es[g1], ff[kb] * Fs[g1]) : 0.f;
                lsum[g0] += p0a + p0b;
                lsum[g1] += p1a + p1b;
                a0u.h2[kk] = __float22bfloat162_rn(make_float2(p0a, p0b));
                a1u.h2[kk] = __float22bfloat162_rn(make_float2(p1a, p1b));
            }
#pragma unroll
            for (int ot = 0; ot < 4; ++ot) {
                acc[g0][ot] = __builtin_amdgcn_mfma_f32_16x16x32_bf16(a0u.v8, b[ot], acc[g0][ot], 0, 0, 0);
                acc[g1][ot] = __builtin_amdgcn_mfma_f32_16x16x32_bf16(a1u.v8, b[ot], acc[g1][ot], 0, 0, 0);
            }
        }
    }

    // complete per-row sums across the 4 quads (disjoint k coverage)
#pragma unroll
    for (int g = 0; g < 8; ++g) {
        lsum[g] += __shfl_xor(lsum[g], 16);
        lsum[g] += __shfl_xor(lsum[g], 32);
    }

    __syncthreads();   // mask reads done; st[] may be reused as stash

    auto stash = [&](int buf) {
#pragma unroll
        for (int g = 0; g < 8; ++g)
#pragma unroll
            for (int ot = 0; ot < 4; ++ot)
#pragma unroll
                for (int r = 0; r < 4; ++r)
                    st[buf][(g * 16 + quad * 4 + r) * 68 + ot * 16 + row16] = acc[g][ot][r];
        if (quad == 0)
#pragma unroll
            for (int g = 0; g < 8; ++g)
                lds_l[buf][g * 16 + row16] = lsum[g];
    };
    auto addin = [&](int buf) {
#pragma unroll
        for (int g = 0; g < 8; ++g) {
#pragma unroll
            for (int ot = 0; ot < 4; ++ot)
#pragma unroll
                for (int r = 0; r < 4; ++r)
                    acc[g][ot][r] += st[buf][(g * 16 + quad * 4 + r) * 68 + ot * 16 + row16];
            lsum[g] += lds_l[buf][g * 16 + row16];
        }
    };

    if (seg == 1) stash(0);
    if (seg == 3) stash(1);
    __syncthreads();
    if (seg == 0) addin(0);
    if (seg == 2) addin(1);
    __syncthreads();
    if (seg == 5) stash(0);
    if (seg == 7) stash(1);
    __syncthreads();
    if (seg == 4) addin(0);
    if (seg == 6) addin(1);
    __syncthreads();
    if (seg == 2) stash(0);
    if (seg == 6) stash(1);
    __syncthreads();
    if (seg == 0) addin(0);
    if (seg == 4) addin(1);
    __syncthreads();
    if (seg == 4) stash(0);
    __syncthreads();
    if (seg == 0) {
        addin(0);
        // epilogue: divide by l, ELU, deposit final tile into st[0]
#pragma unroll
        for (int g = 0; g < 8; ++g)
#pragma unroll
            for (int r = 0; r < 4; ++r) {
                int   qr  = quad * 4 + r;
                float l   = __shfl(lsum[g], qr);    // lane qr holds row qr's sum
                float rl  = 1.0f / l;
#pragma unroll
                for (int ot = 0; ot < 4; ++ot) {
                    float v = acc[g][ot][r] * rl;
                    float y = v > 0.f ? v : __expf(v) - 1.f;
                    st[0][(g * 16 + qr) * 68 + ot * 16 + row16] = y;
                }
            }
    }
    __syncthreads();
    // cooperative coalesced store: 2048 float4s by 512 threads
#pragma unroll
    for (int p = 0; p < 4; ++p) {
        int f    = tid + p * 512;
        int row  = f >> 4;
        int col4 = (f & 15) * 4;
        float4 v = *(const float4*)&st[0][row * 68 + col4];
        *(float4*)&out[(size_t)(tile * 128 + row) * (HH * FOUT) + h * FOUT + col4] = v;
    }
}

// ---------------------------------------------------------------------------
extern "C" void kernel_launch(void* const* d_in, const int* in_sizes, int n_in,
                              void* d_out, int out_size, void* d_ws, size_t ws_size,
                              hipStream_t stream) {
    const float* features = (const float*)d_in[0];
    int*         adj      = (int*)d_in[1];     // packed in place by k_prep
    const float* W        = (const float*)d_in[2];
    const float* a_src    = (const float*)d_in[3];
    const float* a_dst    = (const float*)d_in[4];
    float*       out      = (float*)d_out;

    // Workspace: exactly the proven 4.75 MB footprint
    char* ws = (char*)d_ws;
    __hip_bfloat16* WT   = (__hip_bfloat16*)(ws);                             // 512 KB
    unsigned short* WhT  = (unsigned short*)(ws + (512 << 10));               // 4 MB
    float*          srcv = (float*)(ws + (512 << 10) + (4 << 20));            // 128 KB
    unsigned short* Ebf  = (unsigned short*)(ws + (512 << 10) + (4 << 20) + (128 << 10));  // 64 KB
    unsigned short* Fbf  = (unsigned short*)(ws + (512 << 10) + (4 << 20) + (192 << 10));  // 64 KB

    k_transpose_w<<<dim3(64), 256, 0, stream>>>(W, WT);
    k_prep<<<dim3(2048 + 256), 256, 0, stream>>>(adj, features, WT, a_src, a_dst,
                                                 WhT, srcv, Ebf, Fbf);
    k_flash<<<dim3(32, 8), 512, 0, stream>>>((const unsigned*)adj, srcv, Ebf, Fbf,
                                             WhT, out);
}